// Round 7
// baseline (94.558 us; speedup 1.0000x reference)
//
#include <hip/hip_runtime.h>

#define NT   512
#define NBLK 4096   // B/8

typedef _Float16 half8 __attribute__((ext_vector_type(8)));
typedef _Float16 half4 __attribute__((ext_vector_type(4)));
typedef float    f32x4 __attribute__((ext_vector_type(4)));

// ---- LDS float offsets (21.5 KB) ----
#define L_AH   0          // 2048 f: Ah f16 swz [64][128B]
#define L_DPH  2048       // 1024 f: dpH f16 swz [32][128B]
#define S_BD1  3072       // 128
#define S_BD2  3200       // 128
#define S_C0   3328       // 64
#define S_C1   3392       // 64
#define S_WC   3456       // 2048
#define LDS_FLOATS 5504   // 22016 B

// ---- ws float offsets ----
#define WS_CS   2048    // c0/c1 (128 f)
#define WS_W2F  2304    // Wd2T A-frags f16 (8192 f = 32KB): [(jt2*8+nt)*64+l]
#define WS_W1F  10496   // Wd1T A-frags f16 (8192 f): [(ks*8+jt)*64+l]
#define WS_WMF  18688   // Wm B-frags f16 (2048 f = 8KB)

__global__ void frap_setup(const float* __restrict__ Ws0, const float* __restrict__ bs,
                           const float* __restrict__ Wm,  const float* __restrict__ bm,
                           const float* __restrict__ rel, const float* __restrict__ Wr1,
                           const float* __restrict__ br1, const float* __restrict__ Wr2,
                           const float* __restrict__ br2, const float* __restrict__ Wc,
                           const float* __restrict__ Wd1, const float* __restrict__ Wd2,
                           float* __restrict__ wsf)
{
    __shared__ float hr1[128];
    const int t = threadIdx.x;  // 128 threads
    if (blockIdx.x == 16) {
        const int s = t >> 6, e = t & 63;
        float acc = bm[e];
        for (int h = 0; h < 64; ++h) {
            float hs = fmaxf((s ? Ws0[h] : 0.0f) + bs[h], 0.0f);
            acc = fmaf(hs, Wm[(64 + h) * 64 + e], acc);
        }
        wsf[WS_CS + s * 64 + e] = acc;
    } else if (blockIdx.x == 17) {
        // W2F': K16 A-frag pairs of Wd2T: lane l holds Wd2[j][n],
        // j = jt2*32 + (kk>>2)*16 + (l>>4)*4 + (kk&3), n = nt*16 + (l&15)
        for (int f = t; f < 2048; f += 128) {
            const int l = f & 63, nt = (f >> 6) & 7, jt2 = f >> 9;
            half8 v;
#pragma unroll
            for (int kk = 0; kk < 8; ++kk) {
                const int j = jt2 * 32 + (kk >> 2) * 16 + (l >> 4) * 4 + (kk & 3);
                v[kk] = (_Float16)Wd2[j * 128 + nt * 16 + (l & 15)];
            }
            *(half8*)((char*)wsf + WS_W2F * 4 + f * 16) = v;
        }
    } else if (blockIdx.x == 18) {
        // W1F: K32 frags of Wd1 (k=e, col=j), layout [(ks*8+tile)*64+l]
        for (int f = t; f < 2048; f += 128) {
            const int l = f & 63, tile = (f >> 6) & 7, ks = f >> 9;
            const int kbase = ks * 32 + (l >> 4) * 8, col = tile * 16 + (l & 15);
            half8 v;
#pragma unroll
            for (int kk = 0; kk < 8; ++kk)
                v[kk] = (_Float16)Wd1[(kbase + kk) * 128 + col];
            *(half8*)((char*)wsf + WS_W1F * 4 + f * 16) = v;
        }
    } else if (blockIdx.x == 19) {
        // Wm_top[64k][64col] fragments: f = (tile*2+ks)*64 + lane
        for (int f = t; f < 512; f += 128) {
            const int l = f & 63, ks = (f >> 6) & 1, tile = f >> 7;
            const int kbase = (ks * 4 + (l >> 4)) * 8, col = tile * 16 + (l & 15);
            half8 v;
#pragma unroll
            for (int kk = 0; kk < 8; ++kk)
                v[kk] = (_Float16)Wm[(kbase + kk) * 64 + col];
            *(half8*)((char*)wsf + WS_WMF * 4 + f * 16) = v;
        }
    } else {
        const int pair = blockIdx.x;  // p*4+q
        float a = br1[t];
        for (int r = 0; r < 32; ++r) a = fmaf(rel[pair * 32 + r], Wr1[r * 128 + t], a);
        hr1[t] = fmaxf(a, 0.0f);
        __syncthreads();
        float a2 = br2[t];
        for (int j = 0; j < 128; ++j) a2 = fmaf(hr1[j], Wr2[j * 128 + t], a2);
        wsf[pair * 128 + t] = fmaxf(a2, 0.0f) * Wc[t];  // wc_eff
    }
}

__global__ __launch_bounds__(NT, 6)
void frap_main(const float* __restrict__ mc_g, const float* __restrict__ oh_g,
               const float* __restrict__ Wv_g, const float* __restrict__ bv_g,
               const float* __restrict__ bd1_g, const float* __restrict__ bd2_g,
               const float* __restrict__ bc_g,
               const float* __restrict__ wsf, float* __restrict__ out)
{
    extern __shared__ float lds[];
    const int t = threadIdx.x;
    const int wv = t >> 6, ln = t & 63;
    const int bid = blockIdx.x;

    // ---- consts ----
    if (t < 128) lds[S_BD1 + t] = bd1_g[t];
    else if (t < 256) lds[S_BD2 + (t - 128)] = bd2_g[t - 128];
    else if (t < 384) lds[S_C0 + (t - 256)] = wsf[WS_CS + (t - 256)];
    for (int i = t; i < 2048; i += NT) lds[S_WC + i] = wsf[i];
    const float bcv = bc_g[0];

    // ---- Ah[r=b*8+mv][64h] = relu(mc*Wv+bv) f16 swz ----
    {
        const int r = t >> 3, h8 = (t & 7) * 8;
        const float mcv = mc_g[bid * 64 + r];
        float4 wa = *(const float4*)&Wv_g[h8];
        float4 wb = *(const float4*)&Wv_g[h8 + 4];
        float4 ba = *(const float4*)&bv_g[h8];
        float4 bb = *(const float4*)&bv_g[h8 + 4];
        half8 v;
        v[0] = (_Float16)fmaxf(fmaf(mcv, wa.x, ba.x), 0.f);
        v[1] = (_Float16)fmaxf(fmaf(mcv, wa.y, ba.y), 0.f);
        v[2] = (_Float16)fmaxf(fmaf(mcv, wa.z, ba.z), 0.f);
        v[3] = (_Float16)fmaxf(fmaf(mcv, wa.w, ba.w), 0.f);
        v[4] = (_Float16)fmaxf(fmaf(mcv, wb.x, bb.x), 0.f);
        v[5] = (_Float16)fmaxf(fmaf(mcv, wb.y, bb.y), 0.f);
        v[6] = (_Float16)fmaxf(fmaf(mcv, wb.z, bb.z), 0.f);
        v[7] = (_Float16)fmaxf(fmaf(mcv, wb.w, bb.w), 0.f);
        *(half8*)((char*)lds + L_AH * 4 + r * 128 + (((t & 7) ^ (r & 7)) << 4)) = v;
    }
    __syncthreads();

    const int lr = ln & 15, lq = ln >> 4;

    // ---- phase-1 MFMA: d_p -> dpH (B-frags from global WmF) ----
    {
        const int rt1 = wv & 3, ch = wv >> 2;
        f32x4 acc[2];
        acc[0] = (f32x4){0.f, 0.f, 0.f, 0.f};
        acc[1] = (f32x4){0.f, 0.f, 0.f, 0.f};
#pragma unroll
        for (int ks = 0; ks < 2; ++ks) {
            const int c8 = ks * 4 + lq;
            const int r = rt1 * 16 + lr;
            half8 af = *(half8*)((char*)lds + L_AH * 4 + r * 128 + ((c8 ^ (r & 7)) << 4));
#pragma unroll
            for (int cti = 0; cti < 2; ++cti) {
                const int tile = ch * 2 + cti;
                half8 bf = *(const half8*)((const char*)wsf + WS_WMF * 4
                                           + ((tile * 2 + ks) * 64 + ln) * 16);
                acc[cti] = __builtin_amdgcn_mfma_f32_16x16x32_f16(af, bf, acc[cti], 0, 0, 0);
            }
        }
        const int bloc = rt1 * 2 + (lq >> 1);
#pragma unroll
        for (int pp = 0; pp < 2; ++pp) {
            const int p = (lq & 1) * 2 + pp;
            const float sv = oh_g[(bid * 8 + bloc) * 4 + p];
            const int csb = (sv > 0.5f) ? S_C1 : S_C0;
            const int row32 = p * 8 + bloc, sw = row32 & 7;
#pragma unroll
            for (int cti = 0; cti < 2; ++cti) {
                const int e = (ch * 2 + cti) * 16 + lr;
                const float cs = lds[csb + e];
                float d0 = fmaxf(acc[cti][2 * pp] + cs, 0.f);
                float d1 = fmaxf(acc[cti][2 * pp + 1] + cs, 0.f);
                *(_Float16*)((char*)lds + L_DPH * 4 + row32 * 128
                             + (((e >> 3) ^ sw) << 4) + (e & 7) * 2) = (_Float16)(d0 + d1);
            }
        }
    }
    __syncthreads();   // dpH visible — last barrier

    const int rt = wv;   // wave owns batch-row tile rt (16 pqb rows)

    // ---- GEMM-1': T1 = Wd1T @ A2T  (T1[j][r], per wave: all 8 j-tiles, 1 r-tile) ----
    f32x4 T1[8];
#pragma unroll
    for (int jt = 0; jt < 8; ++jt) T1[jt] = (f32x4){0.f, 0.f, 0.f, 0.f};

#pragma unroll
    for (int ks = 0; ks < 4; ++ks) {
        const int c8 = (ks & 1) * 4 + lq;
        const int r = rt * 16 + lr;
        const int pq = (ks < 2) ? (r >> 5) : ((r >> 3) & 3);
        const int row32 = pq * 8 + (r & 7);
        half8 bfr = *(half8*)((char*)lds + L_DPH * 4 + row32 * 128 + ((c8 ^ (row32 & 7)) << 4));
#pragma unroll
        for (int jt = 0; jt < 8; ++jt) {
            half8 afr = *(const half8*)((const char*)wsf + WS_W1F * 4
                                        + ((ks * 8 + jt) * 64 + ln) * 16);
            T1[jt] = __builtin_amdgcn_mfma_f32_16x16x32_f16(afr, bfr, T1[jt], 0, 0, 0);
        }
    }

    // ---- in-register: pb[jt] = f16(relu(T1 + bd1))  == B-frags for K16 GEMM-2' ----
    half4 pb[8];
#pragma unroll
    for (int jt = 0; jt < 8; ++jt) {
        f32x4 b1 = *(f32x4*)&lds[S_BD1 + jt * 16 + lq * 4];
#pragma unroll
        for (int r2 = 0; r2 < 4; ++r2)
            pb[jt][r2] = (_Float16)fmaxf(T1[jt][r2] + b1[r2], 0.f);
    }

    // ---- GEMM-2': Hd2T = Wd2T @ Hd1T, K16 MFMAs, A-frags from global W2F ----
    f32x4 acc2[8];
#pragma unroll
    for (int nt = 0; nt < 8; ++nt) acc2[nt] = (f32x4){0.f, 0.f, 0.f, 0.f};

#pragma unroll
    for (int jt2 = 0; jt2 < 4; ++jt2) {
#pragma unroll
        for (int nt = 0; nt < 8; ++nt) {
            half8 w2 = *(const half8*)((const char*)wsf + WS_W2F * 4
                                       + ((jt2 * 8 + nt) * 64 + ln) * 16);
            half4 alo, ahi;
            alo[0] = w2[0]; alo[1] = w2[1]; alo[2] = w2[2]; alo[3] = w2[3];
            ahi[0] = w2[4]; ahi[1] = w2[5]; ahi[2] = w2[6]; ahi[3] = w2[7];
            acc2[nt] = __builtin_amdgcn_mfma_f32_16x16x16f16(alo, pb[2 * jt2], acc2[nt], 0, 0, 0);
            acc2[nt] = __builtin_amdgcn_mfma_f32_16x16x16f16(ahi, pb[2 * jt2 + 1], acc2[nt], 0, 0, 0);
        }
    }

    // ---- epilogue: per-lane partial over its 32 n's, 2 shfl for n, relu(+bc), 2 shfl for q-sum ----
    {
        const int pair = rt * 2 + (lr >> 3);
        float tot = 0.f;
#pragma unroll
        for (int nt = 0; nt < 8; ++nt) {
            f32x4 b2 = *(f32x4*)&lds[S_BD2 + nt * 16 + lq * 4];
            f32x4 wc = *(f32x4*)&lds[S_WC + pair * 128 + nt * 16 + lq * 4];
#pragma unroll
            for (int r2 = 0; r2 < 4; ++r2)
                tot = fmaf(fmaxf(acc2[nt][r2] + b2[r2], 0.f), wc[r2], tot);
        }
        tot += __shfl_xor(tot, 16, 64);
        tot += __shfl_xor(tot, 32, 64);
        float ov = fmaxf(tot + bcv, 0.f);
        ov += __shfl_xor(ov, 1, 64);
        ov += __shfl_xor(ov, 2, 64);
        if (ln < 16 && (ln & 3) == 0) {
            const int r = rt * 16 + ln;
            out[(r >> 5) * 32768 + ((r >> 3) & 3) * 8192 + bid * 2 + ((r & 7) >> 2)] = ov;
        }
    }
}

extern "C" void kernel_launch(void* const* d_in, const int* in_sizes, int n_in,
                              void* d_out, int out_size, void* d_ws, size_t ws_size,
                              hipStream_t stream) {
    (void)in_sizes; (void)n_in; (void)out_size; (void)ws_size;
    const float* mc  = (const float*)d_in[0];
    const float* oh  = (const float*)d_in[1];
    const float* Wv  = (const float*)d_in[2];
    const float* bv  = (const float*)d_in[3];
    const float* Ws  = (const float*)d_in[4];
    const float* bs  = (const float*)d_in[5];
    const float* Wm  = (const float*)d_in[6];
    const float* bm  = (const float*)d_in[7];
    const float* rel = (const float*)d_in[8];
    const float* Wd1 = (const float*)d_in[9];
    const float* bd1 = (const float*)d_in[10];
    const float* Wd2 = (const float*)d_in[11];
    const float* bd2 = (const float*)d_in[12];
    const float* Wr1 = (const float*)d_in[13];
    const float* br1 = (const float*)d_in[14];
    const float* Wr2 = (const float*)d_in[15];
    const float* br2 = (const float*)d_in[16];
    const float* Wc  = (const float*)d_in[17];
    const float* bc  = (const float*)d_in[18];
    float* wsf = (float*)d_ws;
    float* out = (float*)d_out;

    hipLaunchKernelGGL(frap_setup, dim3(20), dim3(128), 0, stream,
                       Ws, bs, Wm, bm, rel, Wr1, br1, Wr2, br2, Wc, Wd1, Wd2, wsf);
    hipLaunchKernelGGL(frap_main, dim3(NBLK), dim3(NT), LDS_FLOATS * 4, stream,
                       mc, oh, Wv, bv, bd1, bd2, bc, wsf, out);
}

// Round 8
// 62.140 us; speedup vs baseline: 1.5217x; 1.5217x over previous
//
#include <hip/hip_runtime.h>

#define NT   512
#define NBLK 4096   // B/8

typedef _Float16 half8 __attribute__((ext_vector_type(8)));
typedef _Float16 half4 __attribute__((ext_vector_type(4)));
typedef unsigned short us8 __attribute__((ext_vector_type(8)));
typedef float    f32x4 __attribute__((ext_vector_type(4)));

// ---- LDS float offsets (38.4 KB -> 3 blocks/CU at 6 waves/SIMD) ----
#define L_AH   0          // 2048 f: Ah f16 swz [64][128B]
#define L_DPH  2048       // 1024 f: dpH f16 swz [32][128B]
#define L_UV   3072       // 4096 f: U/V f16 [2][32 col][256B j-row], XOR-swizzled
#define S_BD1  7168       // 128
#define S_BD2  7296       // 128
#define S_C0   7424       // 64
#define S_C1   7488       // 64
#define S_WC   7552       // 2048
#define LDS_FLOATS 9600   // 38400 B

// ---- ws float offsets ----
#define WS_CS   2048    // c0/c1 (128 f)
#define WS_W2F  2304    // Wd2 K32 A-frags f16 (8192 f = 32KB): [(jt32*8+nt)*64+l]
#define WS_W1F  10496   // Wd1 K32 A-frags f16 (8192 f): [((half*2+ks)*8+jt)*64+l]
#define WS_WMF  18688   // Wm B-frags f16 (2048 f = 8KB)

__global__ void frap_setup(const float* __restrict__ Ws0, const float* __restrict__ bs,
                           const float* __restrict__ Wm,  const float* __restrict__ bm,
                           const float* __restrict__ rel, const float* __restrict__ Wr1,
                           const float* __restrict__ br1, const float* __restrict__ Wr2,
                           const float* __restrict__ br2, const float* __restrict__ Wc,
                           const float* __restrict__ Wd1, const float* __restrict__ Wd2,
                           float* __restrict__ wsf)
{
    __shared__ float hr1[128];
    const int t = threadIdx.x;  // 128 threads
    if (blockIdx.x == 16) {
        const int s = t >> 6, e = t & 63;
        float acc = bm[e];
        for (int h = 0; h < 64; ++h) {
            float hs = fmaxf((s ? Ws0[h] : 0.0f) + bs[h], 0.0f);
            acc = fmaf(hs, Wm[(64 + h) * 64 + e], acc);
        }
        wsf[WS_CS + s * 64 + e] = acc;
    } else if (blockIdx.x == 17) {
        // W2F: K32 A-frags of Wd2 (row n, k j): lane l holds
        // Wd2[jt32*32 + (l>>4)*8 + kk][nt*16 + (l&15)]
        for (int idx = t; idx < 2048; idx += 128) {
            const int l = idx & 63, f = idx >> 6;
            const int jt32 = f >> 3, nt = f & 7;
            half8 v;
#pragma unroll
            for (int kk = 0; kk < 8; ++kk)
                v[kk] = (_Float16)Wd2[(jt32 * 32 + (l >> 4) * 8 + kk) * 128 + nt * 16 + (l & 15)];
            *(half8*)((char*)wsf + WS_W2F * 4 + idx * 16) = v;
        }
    } else if (blockIdx.x == 18) {
        // W1F: K32 A-frags of Wd1 halves (row j, k e):
        // Wd1[half*64 + ks*32 + (l>>4)*8 + kk][jt*16 + (l&15)]
        for (int idx = t; idx < 2048; idx += 128) {
            const int l = idx & 63, f = idx >> 6;
            const int half = f >> 4, ks = (f >> 3) & 1, jt = f & 7;
            half8 v;
#pragma unroll
            for (int kk = 0; kk < 8; ++kk)
                v[kk] = (_Float16)Wd1[(half * 64 + ks * 32 + (l >> 4) * 8 + kk) * 128 + jt * 16 + (l & 15)];
            *(half8*)((char*)wsf + WS_W1F * 4 + idx * 16) = v;
        }
    } else if (blockIdx.x == 19) {
        // Wm_top[64k][64col] B-frags: f = (tile*2+ks)*64 + lane
        for (int f = t; f < 512; f += 128) {
            const int l = f & 63, ks = (f >> 6) & 1, tile = f >> 7;
            const int kbase = (ks * 4 + (l >> 4)) * 8, col = tile * 16 + (l & 15);
            half8 v;
#pragma unroll
            for (int kk = 0; kk < 8; ++kk)
                v[kk] = (_Float16)Wm[(kbase + kk) * 64 + col];
            *(half8*)((char*)wsf + WS_WMF * 4 + f * 16) = v;
        }
    } else {
        const int pair = blockIdx.x;  // p*4+q
        float a = br1[t];
        for (int r = 0; r < 32; ++r) a = fmaf(rel[pair * 32 + r], Wr1[r * 128 + t], a);
        hr1[t] = fmaxf(a, 0.0f);
        __syncthreads();
        float a2 = br2[t];
        for (int j = 0; j < 128; ++j) a2 = fmaf(hr1[j], Wr2[j * 128 + t], a2);
        wsf[pair * 128 + t] = fmaxf(a2, 0.0f) * Wc[t];  // wc_eff
    }
}

__global__ __launch_bounds__(NT, 6)
void frap_main(const float* __restrict__ mc_g, const float* __restrict__ oh_g,
               const float* __restrict__ Wv_g, const float* __restrict__ bv_g,
               const float* __restrict__ bd1_g, const float* __restrict__ bd2_g,
               const float* __restrict__ bc_g,
               const float* __restrict__ wsf, float* __restrict__ out)
{
    extern __shared__ float lds[];
    const int t = threadIdx.x;
    const int wv = t >> 6, ln = t & 63;
    const int bid = blockIdx.x;

    // ---- consts ----
    if (t < 128) lds[S_BD1 + t] = bd1_g[t];
    else if (t < 256) lds[S_BD2 + (t - 128)] = bd2_g[t - 128];
    else if (t < 384) lds[S_C0 + (t - 256)] = wsf[WS_CS + (t - 256)];
    for (int i = t; i < 2048; i += NT) lds[S_WC + i] = wsf[i];
    const float bcv = bc_g[0];

    // ---- Ah[r=b*8+mv][64h] = relu(mc*Wv+bv) f16 swz ----
    {
        const int r = t >> 3, h8 = (t & 7) * 8;
        const float mcv = mc_g[bid * 64 + r];
        float4 wa = *(const float4*)&Wv_g[h8];
        float4 wb = *(const float4*)&Wv_g[h8 + 4];
        float4 ba = *(const float4*)&bv_g[h8];
        float4 bb = *(const float4*)&bv_g[h8 + 4];
        half8 v;
        v[0] = (_Float16)fmaxf(fmaf(mcv, wa.x, ba.x), 0.f);
        v[1] = (_Float16)fmaxf(fmaf(mcv, wa.y, ba.y), 0.f);
        v[2] = (_Float16)fmaxf(fmaf(mcv, wa.z, ba.z), 0.f);
        v[3] = (_Float16)fmaxf(fmaf(mcv, wa.w, ba.w), 0.f);
        v[4] = (_Float16)fmaxf(fmaf(mcv, wb.x, bb.x), 0.f);
        v[5] = (_Float16)fmaxf(fmaf(mcv, wb.y, bb.y), 0.f);
        v[6] = (_Float16)fmaxf(fmaf(mcv, wb.z, bb.z), 0.f);
        v[7] = (_Float16)fmaxf(fmaf(mcv, wb.w, bb.w), 0.f);
        *(half8*)((char*)lds + L_AH * 4 + r * 128 + (((t & 7) ^ (r & 7)) << 4)) = v;
    }
    __syncthreads();

    const int lr = ln & 15, lq = ln >> 4;

    // ---- phase-1 MFMA: d_p -> dpH (B-frags from global WmF) ----
    {
        const int rt1 = wv & 3, ch = wv >> 2;
        f32x4 acc[2];
        acc[0] = (f32x4){0.f, 0.f, 0.f, 0.f};
        acc[1] = (f32x4){0.f, 0.f, 0.f, 0.f};
#pragma unroll
        for (int ks = 0; ks < 2; ++ks) {
            const int c8 = ks * 4 + lq;
            const int r = rt1 * 16 + lr;
            half8 af = *(half8*)((char*)lds + L_AH * 4 + r * 128 + ((c8 ^ (r & 7)) << 4));
#pragma unroll
            for (int cti = 0; cti < 2; ++cti) {
                const int tile = ch * 2 + cti;
                half8 bf = *(const half8*)((const char*)wsf + WS_WMF * 4
                                           + ((tile * 2 + ks) * 64 + ln) * 16);
                acc[cti] = __builtin_amdgcn_mfma_f32_16x16x32_f16(af, bf, acc[cti], 0, 0, 0);
            }
        }
        const int bloc = rt1 * 2 + (lq >> 1);
#pragma unroll
        for (int pp = 0; pp < 2; ++pp) {
            const int p = (lq & 1) * 2 + pp;
            const float sv = oh_g[(bid * 8 + bloc) * 4 + p];
            const int csb = (sv > 0.5f) ? S_C1 : S_C0;
            const int row32 = p * 8 + bloc, sw = row32 & 7;
#pragma unroll
            for (int cti = 0; cti < 2; ++cti) {
                const int e = (ch * 2 + cti) * 16 + lr;
                const float cs = lds[csb + e];
                float d0 = fmaxf(acc[cti][2 * pp] + cs, 0.f);
                float d1 = fmaxf(acc[cti][2 * pp + 1] + cs, 0.f);
                *(_Float16*)((char*)lds + L_DPH * 4 + row32 * 128
                             + (((e >> 3) ^ sw) << 4) + (e & 7) * 2) = (_Float16)(d0 + d1);
            }
        }
    }
    __syncthreads();   // dpH visible

    // ---- UV-GEMM (shared across waves): U = Wd1_topT@dpT (+bd1), V = Wd1_botT@dpT ----
    // job per wave: half (U/V) x ct (16 pb-cols) x jh (64 j's) -> 8 MFMAs
    {
        const int half = wv & 1, ct = (wv >> 1) & 1, jh = wv >> 2;
        const int row32 = ct * 16 + lr;
        f32x4 uvacc[4];
#pragma unroll
        for (int j4 = 0; j4 < 4; ++j4) uvacc[j4] = (f32x4){0.f, 0.f, 0.f, 0.f};
#pragma unroll
        for (int ks = 0; ks < 2; ++ks) {
            half8 bfr = *(half8*)((char*)lds + L_DPH * 4 + row32 * 128
                                  + (((ks * 4 + lq) ^ (lr & 7)) << 4));
#pragma unroll
            for (int j4 = 0; j4 < 4; ++j4) {
                half8 afr = *(const half8*)((const char*)wsf + WS_W1F * 4
                            + (((half * 2 + ks) * 8 + jh * 4 + j4) * 64 + ln) * 16);
                uvacc[j4] = __builtin_amdgcn_mfma_f32_16x16x32_f16(afr, bfr, uvacc[j4], 0, 0, 0);
            }
        }
        // store f16 swizzled: [half][col row32][j]; chunk(j>>3) ^= col&7
        const int csw = row32 & 7;
        char* base = (char*)lds + L_UV * 4 + half * 8192 + row32 * 256 + (lq & 1) * 8;
#pragma unroll
        for (int j4 = 0; j4 < 4; ++j4) {
            const int jt = jh * 4 + j4;
            f32x4 v = uvacc[j4];
            if (half == 0) v += *(f32x4*)&lds[S_BD1 + jt * 16 + lq * 4];
            half4 hv;
            hv[0] = (_Float16)v[0]; hv[1] = (_Float16)v[1];
            hv[2] = (_Float16)v[2]; hv[3] = (_Float16)v[3];
            *(half4*)(base + (((jt * 2 + (lq >> 1)) ^ csw) << 4)) = hv;
        }
    }
    __syncthreads();   // U/V visible

    // ---- GEMM-2: Hd2T = Wd2T @ relu(U+V); B-frags built from LDS U/V ----
    const int rt = wv;   // wave owns batch-row tile rt
    const int ucol = (rt >> 1) * 8 + (lr & 7);
    const int vcol = (rt & 1) * 16 + lr;
    char* ub = (char*)lds + L_UV * 4 + ucol * 256;
    char* vb = (char*)lds + L_UV * 4 + 8192 + vcol * 256;

    f32x4 acc2[8];
#pragma unroll
    for (int nt = 0; nt < 8; ++nt) acc2[nt] = (f32x4){0.f, 0.f, 0.f, 0.f};

#pragma unroll
    for (int jt32 = 0; jt32 < 4; ++jt32) {
        const int ch = jt32 * 4 + lq;
        half8 u = *(half8*)(ub + ((ch ^ (ucol & 7)) << 4));
        half8 w = *(half8*)(vb + ((ch ^ (vcol & 7)) << 4));
        half8 s = u + w;                      // v_pk_add_f16
        us8 bbits = __builtin_bit_cast(us8, s);
        us8 m = (bbits >> 15) - (us8)1;       // 0xFFFF if >=0, 0 if negative
        bbits &= m;                           // relu in f16 bits
        s = __builtin_bit_cast(half8, bbits);
#pragma unroll
        for (int nt = 0; nt < 8; ++nt) {
            half8 w2 = *(const half8*)((const char*)wsf + WS_W2F * 4
                                       + ((jt32 * 8 + nt) * 64 + ln) * 16);
            acc2[nt] = __builtin_amdgcn_mfma_f32_16x16x32_f16(w2, s, acc2[nt], 0, 0, 0);
        }
    }

    // ---- epilogue: per-lane partial over its 32 n's, shfl reduce, store ----
    {
        const int pair = rt * 2 + (lr >> 3);
        float tot = 0.f;
#pragma unroll
        for (int nt = 0; nt < 8; ++nt) {
            f32x4 b2 = *(f32x4*)&lds[S_BD2 + nt * 16 + lq * 4];
            f32x4 wc = *(f32x4*)&lds[S_WC + pair * 128 + nt * 16 + lq * 4];
#pragma unroll
            for (int r2 = 0; r2 < 4; ++r2)
                tot = fmaf(fmaxf(acc2[nt][r2] + b2[r2], 0.f), wc[r2], tot);
        }
        tot += __shfl_xor(tot, 16, 64);
        tot += __shfl_xor(tot, 32, 64);
        float ov = fmaxf(tot + bcv, 0.f);
        ov += __shfl_xor(ov, 1, 64);
        ov += __shfl_xor(ov, 2, 64);
        if (ln < 16 && (ln & 3) == 0) {
            const int r = rt * 16 + ln;
            out[(r >> 5) * 32768 + ((r >> 3) & 3) * 8192 + bid * 2 + ((r & 7) >> 2)] = ov;
        }
    }
}

extern "C" void kernel_launch(void* const* d_in, const int* in_sizes, int n_in,
                              void* d_out, int out_size, void* d_ws, size_t ws_size,
                              hipStream_t stream) {
    (void)in_sizes; (void)n_in; (void)out_size; (void)ws_size;
    const float* mc  = (const float*)d_in[0];
    const float* oh  = (const float*)d_in[1];
    const float* Wv  = (const float*)d_in[2];
    const float* bv  = (const float*)d_in[3];
    const float* Ws  = (const float*)d_in[4];
    const float* bs  = (const float*)d_in[5];
    const float* Wm  = (const float*)d_in[6];
    const float* bm  = (const float*)d_in[7];
    const float* rel = (const float*)d_in[8];
    const float* Wd1 = (const float*)d_in[9];
    const float* bd1 = (const float*)d_in[10];
    const float* Wd2 = (const float*)d_in[11];
    const float* bd2 = (const float*)d_in[12];
    const float* Wr1 = (const float*)d_in[13];
    const float* br1 = (const float*)d_in[14];
    const float* Wr2 = (const float*)d_in[15];
    const float* br2 = (const float*)d_in[16];
    const float* Wc  = (const float*)d_in[17];
    const float* bc  = (const float*)d_in[18];
    float* wsf = (float*)d_ws;
    float* out = (float*)d_out;

    hipLaunchKernelGGL(frap_setup, dim3(20), dim3(128), 0, stream,
                       Ws, bs, Wm, bm, rel, Wr1, br1, Wr2, br2, Wc, Wd1, Wd2, wsf);
    hipLaunchKernelGGL(frap_main, dim3(NBLK), dim3(NT), LDS_FLOATS * 4, stream,
                       mc, oh, Wv, bv, bd1, bd2, bc, wsf, out);
}